// Round 3
// baseline (1081.823 us; speedup 1.0000x reference)
//
#include <hip/hip_runtime.h>
#include <math.h>

typedef _Float16 f16;
typedef _Float16 f16x8 __attribute__((ext_vector_type(8)));
typedef _Float16 f16x4 __attribute__((ext_vector_type(4)));
typedef float    f32x4 __attribute__((ext_vector_type(4)));

#define MFMA16(A,B,C) __builtin_amdgcn_mfma_f32_16x16x32_f16(A,B,C,0,0,0)

#define QS   40            // row stride in halfs (80 B: 16B-aligned, bank-clean)
#define HSZ  (32*QS)       // one 32-row region
#define OFFK (6*HSZ)
#define OFFV (12*HSZ)
#define AOS  216           // sAO row stride in halfs (432 B; 22*l15 mod 32 all distinct)

// f16 weight cache offsets (in halfs) inside d_ws
#define W_QKV   0
#define W_QKVC  110592
#define W_PROJ  221184
#define W_PROJC 258048
#define W_TOTAL 294912

__global__ void cvt_weights(const float* __restrict__ a, const float* __restrict__ b,
                            const float* __restrict__ c, const float* __restrict__ d,
                            f16* __restrict__ ws)
{
    int i = blockIdx.x * 256 + threadIdx.x;
    if (i < 110592) {
        ws[W_QKV  + i] = (f16)a[i];
        ws[W_QKVC + i] = (f16)b[i];
    } else {
        int j = i - 110592;
        if (j < 36864) {
            ws[W_PROJ  + j] = (f16)c[j];
            ws[W_PROJC + j] = (f16)d[j];
        }
    }
}

template<bool W16>
__device__ __forceinline__ f16x8 ldw8(const void* base, int idx)
{
    if constexpr (W16) {
        return *(const f16x8*)((const f16*)base + idx);
    } else {
        const float* p = (const float*)base + idx;
        float4 u = *(const float4*)p;
        float4 v = *(const float4*)(p + 4);
        f16x8 r;
        r[0]=(f16)u.x; r[1]=(f16)u.y; r[2]=(f16)u.z; r[3]=(f16)u.w;
        r[4]=(f16)v.x; r[5]=(f16)v.y; r[6]=(f16)v.z; r[7]=(f16)v.w;
        return r;
    }
}

__device__ __forceinline__ f16x8 ldx8(const float* p)
{
    float4 u = *(const float4*)p;
    float4 v = *(const float4*)(p + 4);
    f16x8 r;
    r[0]=(f16)u.x; r[1]=(f16)u.y; r[2]=(f16)u.z; r[3]=(f16)u.w;
    r[4]=(f16)v.x; r[5]=(f16)v.y; r[6]=(f16)v.z; r[7]=(f16)v.w;
    return r;
}

template<bool W16>
__global__ __launch_bounds__(384, 3)
void vsa_kernel(const float* __restrict__ x,
                const float* __restrict__ qkv_w, const float* __restrict__ qkv_b,
                const float* __restrict__ proj_w, const float* __restrict__ proj_b,
                const float* __restrict__ rpb_table, const float* __restrict__ temperature,
                const float* __restrict__ qkvC_w, const float* __restrict__ dw_w,
                const float* __restrict__ projC_w, const float* __restrict__ projC_b,
                const float* __restrict__ gs_w1, const float* __restrict__ gs_b1,
                const float* __restrict__ bn_g, const float* __restrict__ bn_b,
                const float* __restrict__ bn_m, const float* __restrict__ bn_v,
                const float* __restrict__ gs_w2, const float* __restrict__ gs_b2,
                const f16* __restrict__ ws, float* __restrict__ out)
{
    // LDS: 46080 + 13824 + 128 = 60,032 B -> 2 blocks/CU, 12 waves/CU
    __shared__ f16   sQKV[18*HSZ];   // per-head: Q|P|Yq, K|Yk, V^T|Yv  (wave-private)
    __shared__ f16   sAO[32*AOS];    // attn-out [tok][192ch], both branches (shared)
    __shared__ float aspl[32];       // 1 + attn_spatial[token]

    const int t    = threadIdx.x;
    const int h    = t >> 6;         // wave == head, 0..5
    const int lane = t & 63;
    const int l15  = lane & 15;
    const int g    = lane >> 4;      // 0..3

    const float* xb = x + (size_t)blockIdx.x * 6144;
    const f32x4 z4 = {0.f, 0.f, 0.f, 0.f};

    f16* sQ = sQKV + h*HSZ;          // Q (b1) -> P (b1) -> Y-q (b2) -> P_c (b2)
    f16* sK = sQKV + OFFK + h*HSZ;   // K (b1) -> Y-k (b2)
    f16* sV = sQKV + OFFV + h*HSZ;   // V^T (b1) -> Y-v (b2)

    // ---- spatial gate (wave 0): pooled == 1/32 exactly -> batch-independent ----
    if (t < 32) {
        float y1 = gs_b1[t];
        #pragma unroll
        for (int hh = 0; hh < 6; ++hh) y1 += gs_w1[t*54 + hh*9 + 4] * (1.0f/32.0f);
        y1 = (y1 - bn_m[t]) * rsqrtf(bn_v[t] + 1e-5f) * bn_g[t] + bn_b[t];
        float y2 = gs_b2[t];
        #pragma unroll
        for (int c = 0; c < 32; ++c)
            y2 += gs_w2[t*288 + c*9 + 4] * __shfl(y1, c);   // in-wave broadcast, no LDS race
        aspl[t] = 1.0f + y2;
    }

    // ================= GEMM1: this head's q,k,v (6 Mtiles x 2 Ntiles) =================
    {
        f16x8 xf[6][2];
        #pragma unroll
        for (int kt = 0; kt < 6; ++kt)
            #pragma unroll
            for (int nt = 0; nt < 2; ++nt)
                xf[kt][nt] = ldx8(xb + (nt*16 + l15)*192 + kt*32 + g*8);

        const void* wb = W16 ? (const void*)ws : (const void*)qkv_w;
        f32x4 acc[6][2];
        #pragma unroll
        for (int mt = 0; mt < 6; ++mt) { acc[mt][0] = z4; acc[mt][1] = z4; }
        #pragma unroll
        for (int kt = 0; kt < 6; ++kt) {
            f16x8 af[6];
            #pragma unroll
            for (int mt = 0; mt < 6; ++mt)
                af[mt] = ldw8<W16>(wb, ((mt>>1)*192 + h*32 + (mt&1)*16 + l15)*192 + kt*32 + g*8);
            #pragma unroll
            for (int mt = 0; mt < 6; ++mt) {
                acc[mt][0] = MFMA16(af[mt], xf[kt][0], acc[mt][0]);
                acc[mt][1] = MFMA16(af[mt], xf[kt][1], acc[mt][1]);
            }
        }
        const float scale = 0.17677669529663687f;  // 32^-0.5
        #pragma unroll
        for (int mt = 0; mt < 6; ++mt) {
            int which = mt >> 1, sub = mt & 1;
            int chb = which*192 + h*32 + sub*16;
            float4 bi = *(const float4*)(qkv_b + chb + 4*g);
            int db = sub*16 + 4*g;
            #pragma unroll
            for (int nt = 0; nt < 2; ++nt) {
                int token = 16*nt + l15;
                f32x4 a = acc[mt][nt];
                if (which == 0) {
                    f16x4 o;
                    o[0]=(f16)((a[0]+bi.x)*scale); o[1]=(f16)((a[1]+bi.y)*scale);
                    o[2]=(f16)((a[2]+bi.z)*scale); o[3]=(f16)((a[3]+bi.w)*scale);
                    *(f16x4*)(sQ + token*QS + db) = o;
                } else if (which == 1) {
                    f16x4 o;
                    o[0]=(f16)(a[0]+bi.x); o[1]=(f16)(a[1]+bi.y);
                    o[2]=(f16)(a[2]+bi.z); o[3]=(f16)(a[3]+bi.w);
                    *(f16x4*)(sK + token*QS + db) = o;
                } else {   // V stored transposed: [d][token]
                    sV[(db+0)*QS + token] = (f16)(a[0]+bi.x);
                    sV[(db+1)*QS + token] = (f16)(a[1]+bi.y);
                    sV[(db+2)*QS + token] = (f16)(a[2]+bi.z);
                    sV[(db+3)*QS + token] = (f16)(a[3]+bi.w);
                }
            }
        }
    }

    // ================= branch-1 attention (wave-private, no barrier) =================
    {
        f16x8 qa[2], kb[2];
        #pragma unroll
        for (int mt = 0; mt < 2; ++mt)
            qa[mt] = *(const f16x8*)(sQ + (16*mt + l15)*QS + 8*g);
        #pragma unroll
        for (int nt = 0; nt < 2; ++nt)
            kb[nt] = *(const f16x8*)(sK + (16*nt + l15)*QS + 8*g);
        f32x4 s[2][2];
        #pragma unroll
        for (int mt = 0; mt < 2; ++mt)
            #pragma unroll
            for (int nt = 0; nt < 2; ++nt)
                s[mt][nt] = MFMA16(qa[mt], kb[nt], z4);

        float pr[2][2][4];
        #pragma unroll
        for (int mt = 0; mt < 2; ++mt)
            #pragma unroll
            for (int nt = 0; nt < 2; ++nt)
                #pragma unroll
                for (int r = 0; r < 4; ++r) {
                    int m = 16*mt + 4*g + r, n = 16*nt + l15;
                    int dh = (m>>3) - (n>>3) + 3;
                    int dwd = (m&7) - (n&7) + 7;
                    pr[mt][nt][r] = s[mt][nt][r] + rpb_table[(dh*15+dwd)*6 + h];
                }
        #pragma unroll
        for (int mt = 0; mt < 2; ++mt)
            #pragma unroll
            for (int r = 0; r < 4; ++r) {
                float mx = fmaxf(pr[mt][0][r], pr[mt][1][r]);
                mx = fmaxf(mx, __shfl_xor(mx, 1));
                mx = fmaxf(mx, __shfl_xor(mx, 2));
                mx = fmaxf(mx, __shfl_xor(mx, 4));
                mx = fmaxf(mx, __shfl_xor(mx, 8));
                float e0 = __expf(pr[mt][0][r] - mx);
                float e1 = __expf(pr[mt][1][r] - mx);
                float sm = e0 + e1;
                sm += __shfl_xor(sm, 1);
                sm += __shfl_xor(sm, 2);
                sm += __shfl_xor(sm, 4);
                sm += __shfl_xor(sm, 8);
                float inv = 1.0f / sm;
                pr[mt][0][r] = e0*inv;
                pr[mt][1][r] = e1*inv;
            }
        // P overwrites Q region (qa already in regs; wave-private)
        #pragma unroll
        for (int mt = 0; mt < 2; ++mt)
            #pragma unroll
            for (int nt = 0; nt < 2; ++nt)
                #pragma unroll
                for (int r = 0; r < 4; ++r)
                    sQ[(16*mt + 4*g + r)*QS + 16*nt + l15] = (f16)pr[mt][nt][r];

        // O^T = V^T @ P^T
        f16x8 va[2], pb[2];
        #pragma unroll
        for (int mt = 0; mt < 2; ++mt)
            va[mt] = *(const f16x8*)(sV + (16*mt + l15)*QS + 8*g);
        #pragma unroll
        for (int nt = 0; nt < 2; ++nt)
            pb[nt] = *(const f16x8*)(sQ + (16*nt + l15)*QS + 8*g);
        #pragma unroll
        for (int mt = 0; mt < 2; ++mt)
            #pragma unroll
            for (int nt = 0; nt < 2; ++nt) {
                f32x4 o = MFMA16(va[mt], pb[nt], z4);
                int token = 16*nt + l15;
                int dbv = 16*mt + 4*g;
                f16x4 ov;
                ov[0]=(f16)o[0]; ov[1]=(f16)o[1]; ov[2]=(f16)o[2]; ov[3]=(f16)o[3];
                *(f16x4*)(sAO + token*AOS + h*32 + dbv) = ov;
            }
    }
    __syncthreads();   // bar1: sAO (branch1) complete across waves

    // ================= proj GEMM (wave h -> cols 32h..32h+31) =================
    f32x4 acc1[2][2];
    {
        const void* wb = W16 ? (const void*)(ws + W_PROJ) : (const void*)proj_w;
        #pragma unroll
        for (int ct = 0; ct < 2; ++ct) {
            float bi = proj_b[32*h + 16*ct + l15];
            f32x4 b4 = {bi, bi, bi, bi};
            acc1[0][ct] = b4; acc1[1][ct] = b4;
        }
        #pragma unroll
        for (int kt = 0; kt < 6; ++kt) {
            f16x8 aa[2], bb[2];
            #pragma unroll
            for (int mt = 0; mt < 2; ++mt)
                aa[mt] = *(const f16x8*)(sAO + (16*mt + l15)*AOS + kt*32 + 8*g);
            #pragma unroll
            for (int ct = 0; ct < 2; ++ct)
                bb[ct] = ldw8<W16>(wb, (32*h + 16*ct + l15)*192 + kt*32 + 8*g);
            #pragma unroll
            for (int mt = 0; mt < 2; ++mt)
                #pragma unroll
                for (int ct = 0; ct < 2; ++ct)
                    acc1[mt][ct] = MFMA16(aa[mt], bb[ct], acc1[mt][ct]);
        }
    }

    // ================= GEMM1C: this head's y rows -> [ch][token] in own regions ======
    {
        f16x8 xf2[6][2];
        #pragma unroll
        for (int kt = 0; kt < 6; ++kt)
            #pragma unroll
            for (int nt = 0; nt < 2; ++nt)
                xf2[kt][nt] = ldx8(xb + (nt*16 + l15)*192 + kt*32 + g*8);

        const void* wb = W16 ? (const void*)(ws + W_QKVC) : (const void*)qkvC_w;
        f32x4 acc[6][2];
        #pragma unroll
        for (int mt = 0; mt < 6; ++mt) { acc[mt][0] = z4; acc[mt][1] = z4; }
        #pragma unroll
        for (int kt = 0; kt < 6; ++kt) {
            f16x8 af[6];
            #pragma unroll
            for (int mt = 0; mt < 6; ++mt)
                af[mt] = ldw8<W16>(wb, ((mt>>1)*192 + h*32 + (mt&1)*16 + l15)*192 + kt*32 + g*8);
            #pragma unroll
            for (int mt = 0; mt < 6; ++mt) {
                acc[mt][0] = MFMA16(af[mt], xf2[kt][0], acc[mt][0]);
                acc[mt][1] = MFMA16(af[mt], xf2[kt][1], acc[mt][1]);
            }
        }
        #pragma unroll
        for (int mt = 0; mt < 6; ++mt) {
            int which = mt >> 1, sub = mt & 1;
            f16* base = (which == 0) ? sQ : ((which == 1) ? sK : sV);
            #pragma unroll
            for (int nt = 0; nt < 2; ++nt) {
                int token = 16*nt + l15;
                f32x4 a = acc[mt][nt];
                base[(sub*16 + 4*g + 0)*QS + token] = (f16)a[0];
                base[(sub*16 + 4*g + 1)*QS + token] = (f16)a[1];
                base[(sub*16 + 4*g + 2)*QS + token] = (f16)a[2];
                base[(sub*16 + 4*g + 3)*QS + token] = (f16)a[3];
            }
        }
    }

    // ================= branch-2 (MDTA), wave-private =================
    f32x4 o2[2][2];
    {
        f16x8 qa[2], kb[2], vb[2];
        // depthwise 3x3 -> l2norm -> q/k fragments (row=16mt+l15, n=8g+b)
        #pragma unroll
        for (int mt = 0; mt < 2; ++mt) {
            int d = 16*mt + l15;
            #pragma unroll
            for (int qk = 0; qk < 2; ++qk) {
                int ch = qk*192 + h*32 + d;
                const f16* yr = (qk == 0) ? (sQ + d*QS) : (sK + d*QS);
                float wr[9];
                #pragma unroll
                for (int i2 = 0; i2 < 9; ++i2) wr[i2] = dw_w[ch*9 + i2];
                float z[8], ss = 0.f;
                #pragma unroll
                for (int b2 = 0; b2 < 8; ++b2) {
                    float s2 = 0.f;
                    #pragma unroll
                    for (int dh2 = 0; dh2 < 3; ++dh2) {
                        int h2 = g + dh2 - 1;
                        if (h2 >= 0 && h2 < 4) {
                            #pragma unroll
                            for (int dw2 = 0; dw2 < 3; ++dw2) {
                                int w2 = b2 + dw2 - 1;
                                if (w2 >= 0 && w2 < 8)
                                    s2 += wr[dh2*3 + dw2] * (float)yr[h2*8 + w2];
                            }
                        }
                    }
                    z[b2] = s2; ss += s2*s2;
                }
                ss += __shfl_xor(ss, 16);
                ss += __shfl_xor(ss, 32);
                float inv = 1.0f / fmaxf(sqrtf(ss), 1e-12f);
                if (qk == 0) {
                    #pragma unroll
                    for (int b2 = 0; b2 < 8; ++b2) qa[mt][b2] = (f16)(z[b2]*inv);
                } else {
                    #pragma unroll
                    for (int b2 = 0; b2 < 8; ++b2) kb[mt][b2] = (f16)(z[b2]*inv);
                }
            }
        }
        // vc fragments (d'=8g+b, n=16nt+l15)
        #pragma unroll
        for (int nt = 0; nt < 2; ++nt) {
            int n = 16*nt + l15;
            int nh = n >> 3, nw = n & 7;
            #pragma unroll
            for (int b2 = 0; b2 < 8; ++b2) {
                int dv = 8*g + b2;
                int ch = 384 + h*32 + dv;
                const float* wp = dw_w + ch*9;
                const f16* yr = sV + dv*QS;
                float s2 = 0.f;
                #pragma unroll
                for (int dh2 = 0; dh2 < 3; ++dh2) {
                    int h2 = nh + dh2 - 1;
                    if (h2 >= 0 && h2 < 4) {
                        #pragma unroll
                        for (int dw2 = 0; dw2 < 3; ++dw2) {
                            int w2 = nw + dw2 - 1;
                            if (w2 >= 0 && w2 < 8)
                                s2 += wp[dh2*3 + dw2] * (float)yr[h2*8 + w2];
                        }
                    }
                }
                vb[nt][b2] = (f16)s2;
            }
        }
        // S_c = qc kc^T * temp + |d-d'|*dlog ; softmax over d'
        float temph = temperature[h];
        float dlog  = logf(1.0f - exp2f(-2.0f - (2.0f*(float)h)/3.0f));
        f32x4 s[2][2];
        #pragma unroll
        for (int mt = 0; mt < 2; ++mt)
            #pragma unroll
            for (int nt = 0; nt < 2; ++nt)
                s[mt][nt] = MFMA16(qa[mt], kb[nt], z4);
        float pr[2][2][4];
        #pragma unroll
        for (int mt = 0; mt < 2; ++mt)
            #pragma unroll
            for (int nt = 0; nt < 2; ++nt)
                #pragma unroll
                for (int r = 0; r < 4; ++r) {
                    int di = 16*mt + 4*g + r, dj = 16*nt + l15;
                    pr[mt][nt][r] = s[mt][nt][r]*temph + fabsf((float)(di - dj))*dlog;
                }
        #pragma unroll
        for (int mt = 0; mt < 2; ++mt)
            #pragma unroll
            for (int r = 0; r < 4; ++r) {
                float mx = fmaxf(pr[mt][0][r], pr[mt][1][r]);
                mx = fmaxf(mx, __shfl_xor(mx, 1));
                mx = fmaxf(mx, __shfl_xor(mx, 2));
                mx = fmaxf(mx, __shfl_xor(mx, 4));
                mx = fmaxf(mx, __shfl_xor(mx, 8));
                float e0 = __expf(pr[mt][0][r] - mx);
                float e1 = __expf(pr[mt][1][r] - mx);
                float sm = e0 + e1;
                sm += __shfl_xor(sm, 1);
                sm += __shfl_xor(sm, 2);
                sm += __shfl_xor(sm, 4);
                sm += __shfl_xor(sm, 8);
                float inv = 1.0f / sm;
                pr[mt][0][r] = e0*inv;
                pr[mt][1][r] = e1*inv;
            }
        // P_c overwrites Y-q region (fully consumed into qa above; wave-private)
        #pragma unroll
        for (int mt = 0; mt < 2; ++mt)
            #pragma unroll
            for (int nt = 0; nt < 2; ++nt)
                #pragma unroll
                for (int r = 0; r < 4; ++r)
                    sQ[(16*mt + 4*g + r)*QS + 16*nt + l15] = (f16)pr[mt][nt][r];
        // x2pre[d][n] = P_c @ vc (keep frags in regs; store after bar2)
        f16x8 pa[2];
        #pragma unroll
        for (int mt = 0; mt < 2; ++mt)
            pa[mt] = *(const f16x8*)(sQ + (16*mt + l15)*QS + 8*g);
        #pragma unroll
        for (int mt = 0; mt < 2; ++mt)
            #pragma unroll
            for (int nt = 0; nt < 2; ++nt)
                o2[mt][nt] = MFMA16(pa[mt], vb[nt], z4);
    }
    __syncthreads();   // bar2: all proj reads of sAO done -> safe to overwrite
    #pragma unroll
    for (int mt = 0; mt < 2; ++mt)
        #pragma unroll
        for (int nt = 0; nt < 2; ++nt) {
            int token = 16*nt + l15;
            int dbv = 16*mt + 4*g;
            f16x4 ov;
            ov[0]=(f16)o2[mt][nt][0]; ov[1]=(f16)o2[mt][nt][1];
            ov[2]=(f16)o2[mt][nt][2]; ov[3]=(f16)o2[mt][nt][3];
            *(f16x4*)(sAO + token*AOS + h*32 + dbv) = ov;
        }
    __syncthreads();   // bar3: sAO (branch2) complete

    // ================= projC GEMM + gate + store =================
    f32x4 acc2[2][2];
    {
        const void* wb = W16 ? (const void*)(ws + W_PROJC) : (const void*)projC_w;
        #pragma unroll
        for (int ct = 0; ct < 2; ++ct) {
            float bi = projC_b[32*h + 16*ct + l15];
            f32x4 b4 = {bi, bi, bi, bi};
            acc2[0][ct] = b4; acc2[1][ct] = b4;
        }
        #pragma unroll
        for (int kt = 0; kt < 6; ++kt) {
            f16x8 aa[2], bb[2];
            #pragma unroll
            for (int mt = 0; mt < 2; ++mt)
                aa[mt] = *(const f16x8*)(sAO + (16*mt + l15)*AOS + kt*32 + 8*g);
            #pragma unroll
            for (int ct = 0; ct < 2; ++ct)
                bb[ct] = ldw8<W16>(wb, (32*h + 16*ct + l15)*192 + kt*32 + 8*g);
            #pragma unroll
            for (int mt = 0; mt < 2; ++mt)
                #pragma unroll
                for (int ct = 0; ct < 2; ++ct)
                    acc2[mt][ct] = MFMA16(aa[mt], bb[ct], acc2[mt][ct]);
        }
    }

    float* ob = out + (size_t)blockIdx.x * 6144;
    #pragma unroll
    for (int mt = 0; mt < 2; ++mt)
        #pragma unroll
        for (int r = 0; r < 4; ++r) {
            int m = 16*mt + 4*g + r;
            float asp = aspl[m];
            #pragma unroll
            for (int ct = 0; ct < 2; ++ct) {
                int c = 32*h + 16*ct + l15;
                ob[m*192 + c] = acc1[mt][ct][r] + acc2[mt][ct][r]*asp;
            }
        }
}

extern "C" void kernel_launch(void* const* d_in, const int* in_sizes, int n_in,
                              void* d_out, int out_size, void* d_ws, size_t ws_size,
                              hipStream_t stream) {
    (void)n_in; (void)out_size;
    const float* x         = (const float*)d_in[0];
    const float* qkv_w     = (const float*)d_in[1];
    const float* qkv_b     = (const float*)d_in[2];
    const float* proj_w    = (const float*)d_in[3];
    const float* proj_b    = (const float*)d_in[4];
    const float* rpb_table = (const float*)d_in[5];
    const float* temp      = (const float*)d_in[6];
    const float* qkvC_w    = (const float*)d_in[7];
    const float* dw_w      = (const float*)d_in[8];
    const float* projC_w   = (const float*)d_in[9];
    const float* projC_b   = (const float*)d_in[10];
    const float* gs_w1     = (const float*)d_in[11];
    const float* gs_b1     = (const float*)d_in[12];
    const float* bn_g      = (const float*)d_in[13];
    const float* bn_b      = (const float*)d_in[14];
    const float* bn_m      = (const float*)d_in[15];
    const float* bn_v      = (const float*)d_in[16];
    const float* gs_w2     = (const float*)d_in[17];
    const float* gs_b2     = (const float*)d_in[18];
    float* out = (float*)d_out;

    int B = in_sizes[0] / (32 * 192);   // 4096
    bool use_ws = (d_ws != nullptr) && (ws_size >= (size_t)W_TOTAL * sizeof(f16));
    if (use_ws) {
        cvt_weights<<<576, 256, 0, stream>>>(qkv_w, qkvC_w, proj_w, projC_w, (f16*)d_ws);
        vsa_kernel<true><<<B, 384, 0, stream>>>(x, qkv_w, qkv_b, proj_w, proj_b,
                                                rpb_table, temp, qkvC_w, dw_w,
                                                projC_w, projC_b, gs_w1, gs_b1,
                                                bn_g, bn_b, bn_m, bn_v, gs_w2, gs_b2,
                                                (const f16*)d_ws, out);
    } else {
        vsa_kernel<false><<<B, 384, 0, stream>>>(x, qkv_w, qkv_b, proj_w, proj_b,
                                                 rpb_table, temp, qkvC_w, dw_w,
                                                 projC_w, projC_b, gs_w1, gs_b1,
                                                 bn_g, bn_b, bn_m, bn_v, gs_w2, gs_b2,
                                                 nullptr, out);
    }
}

// Round 4
// 870.579 us; speedup vs baseline: 1.2426x; 1.2426x over previous
//
#include <hip/hip_runtime.h>
#include <math.h>

typedef _Float16 f16;
typedef _Float16 f16x8 __attribute__((ext_vector_type(8)));
typedef _Float16 f16x4 __attribute__((ext_vector_type(4)));
typedef float    f32x4 __attribute__((ext_vector_type(4)));

#define MFMA16(A,B,C) __builtin_amdgcn_mfma_f32_16x16x32_f16(A,B,C,0,0,0)

#define QS   40            // row stride in halfs (80 B: 16B-aligned, 2-way-bank at worst)
#define HSZ  (32*QS)       // one 32-row region
#define OFFK (6*HSZ)
#define OFFV (12*HSZ)
#define AOS  216           // sAO row stride in halfs (432 B)

// f16 weight cache offsets (in halfs) inside d_ws
#define W_QKV   0
#define W_QKVC  110592
#define W_PROJ  221184
#define W_PROJC 258048
#define W_TOTAL 294912

__global__ void cvt_weights(const float* __restrict__ a, const float* __restrict__ b,
                            const float* __restrict__ c, const float* __restrict__ d,
                            f16* __restrict__ ws)
{
    int i = blockIdx.x * 256 + threadIdx.x;
    if (i < 110592) {
        ws[W_QKV  + i] = (f16)a[i];
        ws[W_QKVC + i] = (f16)b[i];
    } else {
        int j = i - 110592;
        if (j < 36864) {
            ws[W_PROJ  + j] = (f16)c[j];
            ws[W_PROJC + j] = (f16)d[j];
        }
    }
}

template<bool W16>
__device__ __forceinline__ f16x8 ldw8(const void* base, int idx)
{
    if constexpr (W16) {
        return *(const f16x8*)((const f16*)base + idx);
    } else {
        const float* p = (const float*)base + idx;
        float4 u = *(const float4*)p;
        float4 v = *(const float4*)(p + 4);
        f16x8 r;
        r[0]=(f16)u.x; r[1]=(f16)u.y; r[2]=(f16)u.z; r[3]=(f16)u.w;
        r[4]=(f16)v.x; r[5]=(f16)v.y; r[6]=(f16)v.z; r[7]=(f16)v.w;
        return r;
    }
}

__device__ __forceinline__ f16x8 ldx8(const float* p)
{
    float4 u = *(const float4*)p;
    float4 v = *(const float4*)(p + 4);
    f16x8 r;
    r[0]=(f16)u.x; r[1]=(f16)u.y; r[2]=(f16)u.z; r[3]=(f16)u.w;
    r[4]=(f16)v.x; r[5]=(f16)v.y; r[6]=(f16)v.z; r[7]=(f16)v.w;
    return r;
}

template<bool W16>
__global__ __launch_bounds__(384, 2)
void vsa_kernel(const float* __restrict__ x,
                const float* __restrict__ qkv_w, const float* __restrict__ qkv_b,
                const float* __restrict__ proj_w, const float* __restrict__ proj_b,
                const float* __restrict__ rpb_table, const float* __restrict__ temperature,
                const float* __restrict__ qkvC_w, const float* __restrict__ dw_w,
                const float* __restrict__ projC_w, const float* __restrict__ projC_b,
                const float* __restrict__ gs_w1, const float* __restrict__ gs_b1,
                const float* __restrict__ bn_g, const float* __restrict__ bn_b,
                const float* __restrict__ bn_m, const float* __restrict__ bn_v,
                const float* __restrict__ gs_w2, const float* __restrict__ gs_b2,
                const f16* __restrict__ ws, float* __restrict__ out)
{
    // LDS: 46080 + 13824 + 128 = 60,032 B -> 2 blocks/CU, 12 waves/CU
    __shared__ f16   sQKV[18*HSZ];   // per-head: Q|P|Yq, K|Yk, V^T|Yv  (wave-private)
    __shared__ f16   sAO[32*AOS];    // attn-out [tok][192ch], both branches (shared)
    __shared__ float aspl[32];       // 1 + attn_spatial[token]

    const int t    = threadIdx.x;
    const int h    = t >> 6;         // wave == head, 0..5
    const int lane = t & 63;
    const int l15  = lane & 15;
    const int g    = lane >> 4;      // 0..3

    const float* xb = x + (size_t)blockIdx.x * 6144;
    const f32x4 z4 = {0.f, 0.f, 0.f, 0.f};

    f16* sQ = sQKV + h*HSZ;          // Q (b1) -> P (b1) -> Y-q (b2) -> P_c (b2)
    f16* sK = sQKV + OFFK + h*HSZ;   // K (b1) -> Y-k (b2)
    f16* sV = sQKV + OFFV + h*HSZ;   // V^T (b1) -> Y-v (b2)

    // ---- spatial gate (wave 0): pooled == 1/32 exactly -> batch-independent ----
    if (t < 32) {
        float y1 = gs_b1[t];
        #pragma unroll
        for (int hh = 0; hh < 6; ++hh) y1 += gs_w1[t*54 + hh*9 + 4] * (1.0f/32.0f);
        y1 = (y1 - bn_m[t]) * rsqrtf(bn_v[t] + 1e-5f) * bn_g[t] + bn_b[t];
        float y2 = gs_b2[t];
        #pragma unroll
        for (int c = 0; c < 32; ++c)
            y2 += gs_w2[t*288 + c*9 + 4] * __shfl(y1, c);   // in-wave broadcast
        aspl[t] = 1.0f + y2;
    }

    // ================= GEMM1: this head's q,k,v (mt-outer: low reg pressure) ========
    {
        f16x8 xf[6][2];
        #pragma unroll
        for (int kt = 0; kt < 6; ++kt)
            #pragma unroll
            for (int nt = 0; nt < 2; ++nt)
                xf[kt][nt] = ldx8(xb + (nt*16 + l15)*192 + kt*32 + g*8);

        const void* wb = W16 ? (const void*)ws : (const void*)qkv_w;
        const float scale = 0.17677669529663687f;  // 32^-0.5
        #pragma unroll
        for (int mt = 0; mt < 6; ++mt) {
            int which = mt >> 1, sub = mt & 1;
            int chb = which*192 + h*32 + sub*16;
            f32x4 a0 = z4, a1 = z4;
            #pragma unroll
            for (int kt = 0; kt < 6; ++kt) {
                f16x8 af = ldw8<W16>(wb, (chb + l15)*192 + kt*32 + g*8);
                a0 = MFMA16(af, xf[kt][0], a0);
                a1 = MFMA16(af, xf[kt][1], a1);
            }
            float4 bi = *(const float4*)(qkv_b + chb + 4*g);
            int db = sub*16 + 4*g;
            #pragma unroll
            for (int nt = 0; nt < 2; ++nt) {
                int token = 16*nt + l15;
                f32x4 a = (nt == 0) ? a0 : a1;
                if (which == 0) {
                    f16x4 o;
                    o[0]=(f16)((a[0]+bi.x)*scale); o[1]=(f16)((a[1]+bi.y)*scale);
                    o[2]=(f16)((a[2]+bi.z)*scale); o[3]=(f16)((a[3]+bi.w)*scale);
                    *(f16x4*)(sQ + token*QS + db) = o;
                } else if (which == 1) {
                    f16x4 o;
                    o[0]=(f16)(a[0]+bi.x); o[1]=(f16)(a[1]+bi.y);
                    o[2]=(f16)(a[2]+bi.z); o[3]=(f16)(a[3]+bi.w);
                    *(f16x4*)(sK + token*QS + db) = o;
                } else {   // V stored transposed: [d][token]
                    sV[(db+0)*QS + token] = (f16)(a[0]+bi.x);
                    sV[(db+1)*QS + token] = (f16)(a[1]+bi.y);
                    sV[(db+2)*QS + token] = (f16)(a[2]+bi.z);
                    sV[(db+3)*QS + token] = (f16)(a[3]+bi.w);
                }
            }
        }
    }

    // ================= branch-1 attention (wave-private, no barrier) =================
    {
        f16x8 qa[2], kb[2];
        #pragma unroll
        for (int mt = 0; mt < 2; ++mt)
            qa[mt] = *(const f16x8*)(sQ + (16*mt + l15)*QS + 8*g);
        #pragma unroll
        for (int nt = 0; nt < 2; ++nt)
            kb[nt] = *(const f16x8*)(sK + (16*nt + l15)*QS + 8*g);
        f32x4 s[2][2];
        #pragma unroll
        for (int mt = 0; mt < 2; ++mt)
            #pragma unroll
            for (int nt = 0; nt < 2; ++nt)
                s[mt][nt] = MFMA16(qa[mt], kb[nt], z4);

        float pr[2][2][4];
        #pragma unroll
        for (int mt = 0; mt < 2; ++mt)
            #pragma unroll
            for (int nt = 0; nt < 2; ++nt)
                #pragma unroll
                for (int r = 0; r < 4; ++r) {
                    int m = 16*mt + 4*g + r, n = 16*nt + l15;
                    int dh = (m>>3) - (n>>3) + 3;
                    int dwd = (m&7) - (n&7) + 7;
                    pr[mt][nt][r] = s[mt][nt][r] + rpb_table[(dh*15+dwd)*6 + h];
                }
        #pragma unroll
        for (int mt = 0; mt < 2; ++mt)
            #pragma unroll
            for (int r = 0; r < 4; ++r) {
                float mx = fmaxf(pr[mt][0][r], pr[mt][1][r]);
                mx = fmaxf(mx, __shfl_xor(mx, 1));
                mx = fmaxf(mx, __shfl_xor(mx, 2));
                mx = fmaxf(mx, __shfl_xor(mx, 4));
                mx = fmaxf(mx, __shfl_xor(mx, 8));
                float e0 = __expf(pr[mt][0][r] - mx);
                float e1 = __expf(pr[mt][1][r] - mx);
                float sm = e0 + e1;
                sm += __shfl_xor(sm, 1);
                sm += __shfl_xor(sm, 2);
                sm += __shfl_xor(sm, 4);
                sm += __shfl_xor(sm, 8);
                float inv = 1.0f / sm;
                pr[mt][0][r] = e0*inv;
                pr[mt][1][r] = e1*inv;
            }
        // P overwrites Q region (qa already in regs; wave-private)
        #pragma unroll
        for (int mt = 0; mt < 2; ++mt)
            #pragma unroll
            for (int nt = 0; nt < 2; ++nt)
                #pragma unroll
                for (int r = 0; r < 4; ++r)
                    sQ[(16*mt + 4*g + r)*QS + 16*nt + l15] = (f16)pr[mt][nt][r];

        // O^T = V^T @ P^T
        f16x8 va[2], pb[2];
        #pragma unroll
        for (int mt = 0; mt < 2; ++mt)
            va[mt] = *(const f16x8*)(sV + (16*mt + l15)*QS + 8*g);
        #pragma unroll
        for (int nt = 0; nt < 2; ++nt)
            pb[nt] = *(const f16x8*)(sQ + (16*nt + l15)*QS + 8*g);
        #pragma unroll
        for (int mt = 0; mt < 2; ++mt)
            #pragma unroll
            for (int nt = 0; nt < 2; ++nt) {
                f32x4 o = MFMA16(va[mt], pb[nt], z4);
                int token = 16*nt + l15;
                int dbv = 16*mt + 4*g;
                f16x4 ov;
                ov[0]=(f16)o[0]; ov[1]=(f16)o[1]; ov[2]=(f16)o[2]; ov[3]=(f16)o[3];
                *(f16x4*)(sAO + token*AOS + h*32 + dbv) = ov;
            }
    }
    __syncthreads();   // bar1: sAO (branch1) complete across waves

    // ================= proj GEMM (wave h -> cols 32h..32h+31) =================
    f32x4 acc1[2][2];
    {
        const void* wb = W16 ? (const void*)(ws + W_PROJ) : (const void*)proj_w;
        #pragma unroll
        for (int ct = 0; ct < 2; ++ct) {
            float bi = proj_b[32*h + 16*ct + l15];
            f32x4 b4 = {bi, bi, bi, bi};
            acc1[0][ct] = b4; acc1[1][ct] = b4;
        }
        #pragma unroll
        for (int kt = 0; kt < 6; ++kt) {
            f16x8 aa[2], bb[2];
            #pragma unroll
            for (int mt = 0; mt < 2; ++mt)
                aa[mt] = *(const f16x8*)(sAO + (16*mt + l15)*AOS + kt*32 + 8*g);
            #pragma unroll
            for (int ct = 0; ct < 2; ++ct)
                bb[ct] = ldw8<W16>(wb, (32*h + 16*ct + l15)*192 + kt*32 + 8*g);
            #pragma unroll
            for (int mt = 0; mt < 2; ++mt)
                #pragma unroll
                for (int ct = 0; ct < 2; ++ct)
                    acc1[mt][ct] = MFMA16(aa[mt], bb[ct], acc1[mt][ct]);
        }
    }

    // ================= GEMM1C: this head's y rows (mt-outer, low pressure) ==========
    {
        f16x8 xf2[6][2];
        #pragma unroll
        for (int kt = 0; kt < 6; ++kt)
            #pragma unroll
            for (int nt = 0; nt < 2; ++nt)
                xf2[kt][nt] = ldx8(xb + (nt*16 + l15)*192 + kt*32 + g*8);

        const void* wb = W16 ? (const void*)(ws + W_QKVC) : (const void*)qkvC_w;
        #pragma unroll
        for (int mt = 0; mt < 6; ++mt) {
            int which = mt >> 1, sub = mt & 1;
            int chb = which*192 + h*32 + sub*16;
            f32x4 a0 = z4, a1 = z4;
            #pragma unroll
            for (int kt = 0; kt < 6; ++kt) {
                f16x8 af = ldw8<W16>(wb, (chb + l15)*192 + kt*32 + g*8);
                a0 = MFMA16(af, xf2[kt][0], a0);
                a1 = MFMA16(af, xf2[kt][1], a1);
            }
            f16* base = (which == 0) ? sQ : ((which == 1) ? sK : sV);
            #pragma unroll
            for (int nt = 0; nt < 2; ++nt) {
                int token = 16*nt + l15;
                f32x4 a = (nt == 0) ? a0 : a1;
                base[(sub*16 + 4*g + 0)*QS + token] = (f16)a[0];
                base[(sub*16 + 4*g + 1)*QS + token] = (f16)a[1];
                base[(sub*16 + 4*g + 2)*QS + token] = (f16)a[2];
                base[(sub*16 + 4*g + 3)*QS + token] = (f16)a[3];
            }
        }
    }

    // ================= branch-2 (MDTA), wave-private =================
    f32x4 o2[2][2];
    {
        f16x8 qa[2], kb[2], vb[2];
        // depthwise 3x3 -> l2norm -> q/k fragments (row=16mt+l15, n=8g+b)
        #pragma unroll
        for (int mt = 0; mt < 2; ++mt) {
            int d = 16*mt + l15;
            #pragma unroll
            for (int qk = 0; qk < 2; ++qk) {
                int ch = qk*192 + h*32 + d;
                const f16* yr = (qk == 0) ? (sQ + d*QS) : (sK + d*QS);
                float wr[9];
                #pragma unroll
                for (int i2 = 0; i2 < 9; ++i2) wr[i2] = dw_w[ch*9 + i2];
                float z[8], ss = 0.f;
                #pragma unroll
                for (int b2 = 0; b2 < 8; ++b2) {
                    float s2 = 0.f;
                    #pragma unroll
                    for (int dh2 = 0; dh2 < 3; ++dh2) {
                        int h2 = g + dh2 - 1;
                        if (h2 >= 0 && h2 < 4) {
                            #pragma unroll
                            for (int dw2 = 0; dw2 < 3; ++dw2) {
                                int w2 = b2 + dw2 - 1;
                                if (w2 >= 0 && w2 < 8)
                                    s2 += wr[dh2*3 + dw2] * (float)yr[h2*8 + w2];
                            }
                        }
                    }
                    z[b2] = s2; ss += s2*s2;
                }
                ss += __shfl_xor(ss, 16);
                ss += __shfl_xor(ss, 32);
                float inv = 1.0f / fmaxf(sqrtf(ss), 1e-12f);
                if (qk == 0) {
                    #pragma unroll
                    for (int b2 = 0; b2 < 8; ++b2) qa[mt][b2] = (f16)(z[b2]*inv);
                } else {
                    #pragma unroll
                    for (int b2 = 0; b2 < 8; ++b2) kb[mt][b2] = (f16)(z[b2]*inv);
                }
            }
        }
        // vc fragments (d'=8g+b, n=16nt+l15)
        #pragma unroll
        for (int nt = 0; nt < 2; ++nt) {
            int n = 16*nt + l15;
            int nh = n >> 3, nw = n & 7;
            #pragma unroll
            for (int b2 = 0; b2 < 8; ++b2) {
                int dv = 8*g + b2;
                int ch = 384 + h*32 + dv;
                const float* wp = dw_w + ch*9;
                const f16* yr = sV + dv*QS;
                float s2 = 0.f;
                #pragma unroll
                for (int dh2 = 0; dh2 < 3; ++dh2) {
                    int h2 = nh + dh2 - 1;
                    if (h2 >= 0 && h2 < 4) {
                        #pragma unroll
                        for (int dw2 = 0; dw2 < 3; ++dw2) {
                            int w2 = nw + dw2 - 1;
                            if (w2 >= 0 && w2 < 8)
                                s2 += wp[dh2*3 + dw2] * (float)yr[h2*8 + w2];
                        }
                    }
                }
                vb[nt][b2] = (f16)s2;
            }
        }
        // S_c = qc kc^T * temp + |d-d'|*dlog ; softmax over d'
        float temph = temperature[h];
        float dlog  = logf(1.0f - exp2f(-2.0f - (2.0f*(float)h)/3.0f));
        f32x4 s[2][2];
        #pragma unroll
        for (int mt = 0; mt < 2; ++mt)
            #pragma unroll
            for (int nt = 0; nt < 2; ++nt)
                s[mt][nt] = MFMA16(qa[mt], kb[nt], z4);
        float pr[2][2][4];
        #pragma unroll
        for (int mt = 0; mt < 2; ++mt)
            #pragma unroll
            for (int nt = 0; nt < 2; ++nt)
                #pragma unroll
                for (int r = 0; r < 4; ++r) {
                    int di = 16*mt + 4*g + r, dj = 16*nt + l15;
                    pr[mt][nt][r] = s[mt][nt][r]*temph + fabsf((float)(di - dj))*dlog;
                }
        #pragma unroll
        for (int mt = 0; mt < 2; ++mt)
            #pragma unroll
            for (int r = 0; r < 4; ++r) {
                float mx = fmaxf(pr[mt][0][r], pr[mt][1][r]);
                mx = fmaxf(mx, __shfl_xor(mx, 1));
                mx = fmaxf(mx, __shfl_xor(mx, 2));
                mx = fmaxf(mx, __shfl_xor(mx, 4));
                mx = fmaxf(mx, __shfl_xor(mx, 8));
                float e0 = __expf(pr[mt][0][r] - mx);
                float e1 = __expf(pr[mt][1][r] - mx);
                float sm = e0 + e1;
                sm += __shfl_xor(sm, 1);
                sm += __shfl_xor(sm, 2);
                sm += __shfl_xor(sm, 4);
                sm += __shfl_xor(sm, 8);
                float inv = 1.0f / sm;
                pr[mt][0][r] = e0*inv;
                pr[mt][1][r] = e1*inv;
            }
        // P_c overwrites Y-q region (fully consumed into qa above; wave-private)
        #pragma unroll
        for (int mt = 0; mt < 2; ++mt)
            #pragma unroll
            for (int nt = 0; nt < 2; ++nt)
                #pragma unroll
                for (int r = 0; r < 4; ++r)
                    sQ[(16*mt + 4*g + r)*QS + 16*nt + l15] = (f16)pr[mt][nt][r];
        // x2pre[d][n] = P_c @ vc (keep frags in regs; store after bar2)
        f16x8 pa[2];
        #pragma unroll
        for (int mt = 0; mt < 2; ++mt)
            pa[mt] = *(const f16x8*)(sQ + (16*mt + l15)*QS + 8*g);
        #pragma unroll
        for (int mt = 0; mt < 2; ++mt)
            #pragma unroll
            for (int nt = 0; nt < 2; ++nt)
                o2[mt][nt] = MFMA16(pa[mt], vb[nt], z4);
    }
    __syncthreads();   // bar2: all proj reads of sAO done -> safe to overwrite
    #pragma unroll
    for (int mt = 0; mt < 2; ++mt)
        #pragma unroll
        for (int nt = 0; nt < 2; ++nt) {
            int token = 16*nt + l15;
            int dbv = 16*mt + 4*g;
            f16x4 ov;
            ov[0]=(f16)o2[mt][nt][0]; ov[1]=(f16)o2[mt][nt][1];
            ov[2]=(f16)o2[mt][nt][2]; ov[3]=(f16)o2[mt][nt][3];
            *(f16x4*)(sAO + token*AOS + h*32 + dbv) = ov;
        }
    __syncthreads();   // bar3: sAO (branch2) complete

    // ================= projC GEMM + gate + store =================
    f32x4 acc2[2][2];
    {
        const void* wb = W16 ? (const void*)(ws + W_PROJC) : (const void*)projC_w;
        #pragma unroll
        for (int ct = 0; ct < 2; ++ct) {
            float bi = projC_b[32*h + 16*ct + l15];
            f32x4 b4 = {bi, bi, bi, bi};
            acc2[0][ct] = b4; acc2[1][ct] = b4;
        }
        #pragma unroll
        for (int kt = 0; kt < 6; ++kt) {
            f16x8 aa[2], bb[2];
            #pragma unroll
            for (int mt = 0; mt < 2; ++mt)
                aa[mt] = *(const f16x8*)(sAO + (16*mt + l15)*AOS + kt*32 + 8*g);
            #pragma unroll
            for (int ct = 0; ct < 2; ++ct)
                bb[ct] = ldw8<W16>(wb, (32*h + 16*ct + l15)*192 + kt*32 + 8*g);
            #pragma unroll
            for (int mt = 0; mt < 2; ++mt)
                #pragma unroll
                for (int ct = 0; ct < 2; ++ct)
                    acc2[mt][ct] = MFMA16(aa[mt], bb[ct], acc2[mt][ct]);
        }
    }

    float* ob = out + (size_t)blockIdx.x * 6144;
    #pragma unroll
    for (int mt = 0; mt < 2; ++mt)
        #pragma unroll
        for (int r = 0; r < 4; ++r) {
            int m = 16*mt + 4*g + r;
            float asp = aspl[m];
            #pragma unroll
            for (int ct = 0; ct < 2; ++ct) {
                int c = 32*h + 16*ct + l15;
                ob[m*192 + c] = acc1[mt][ct][r] + acc2[mt][ct][r]*asp;
            }
        }
}

extern "C" void kernel_launch(void* const* d_in, const int* in_sizes, int n_in,
                              void* d_out, int out_size, void* d_ws, size_t ws_size,
                              hipStream_t stream) {
    (void)n_in; (void)out_size;
    const float* x         = (const float*)d_in[0];
    const float* qkv_w     = (const float*)d_in[1];
    const float* qkv_b     = (const float*)d_in[2];
    const float* proj_w    = (const float*)d_in[3];
    const float* proj_b    = (const float*)d_in[4];
    const float* rpb_table = (const float*)d_in[5];
    const float* temp      = (const float*)d_in[6];
    const float* qkvC_w    = (const float*)d_in[7];
    const float* dw_w      = (const float*)d_in[8];
    const float* projC_w   = (const float*)d_in[9];
    const float* projC_b   = (const float*)d_in[10];
    const float* gs_w1     = (const float*)d_in[11];
    const float* gs_b1     = (const float*)d_in[12];
    const float* bn_g      = (const float*)d_in[13];
    const float* bn_b      = (const float*)d_in[14];
    const float* bn_m      = (const float*)d_in[15];
    const float* bn_v      = (const float*)d_in[16];
    const float* gs_w2     = (const float*)d_in[17];
    const float* gs_b2     = (const float*)d_in[18];
    float* out = (float*)d_out;

    int B = in_sizes[0] / (32 * 192);   // 4096
    bool use_ws = (d_ws != nullptr) && (ws_size >= (size_t)W_TOTAL * sizeof(f16));
    if (use_ws) {
        cvt_weights<<<576, 256, 0, stream>>>(qkv_w, qkvC_w, proj_w, projC_w, (f16*)d_ws);
        vsa_kernel<true><<<B, 384, 0, stream>>>(x, qkv_w, qkv_b, proj_w, proj_b,
                                                rpb_table, temp, qkvC_w, dw_w,
                                                projC_w, projC_b, gs_w1, gs_b1,
                                                bn_g, bn_b, bn_m, bn_v, gs_w2, gs_b2,
                                                (const f16*)d_ws, out);
    } else {
        vsa_kernel<false><<<B, 384, 0, stream>>>(x, qkv_w, qkv_b, proj_w, proj_b,
                                                 rpb_table, temp, qkvC_w, dw_w,
                                                 projC_w, projC_b, gs_w1, gs_b1,
                                                 bn_g, bn_b, bn_m, bn_v, gs_w2, gs_b2,
                                                 nullptr, out);
    }
}

// Round 5
// 500.996 us; speedup vs baseline: 2.1593x; 1.7377x over previous
//
#include <hip/hip_runtime.h>
#include <math.h>

typedef _Float16 f16;
typedef _Float16 f16x8 __attribute__((ext_vector_type(8)));
typedef _Float16 f16x4 __attribute__((ext_vector_type(4)));
typedef float    f32x4 __attribute__((ext_vector_type(4)));

#define MFMA16(A,B,C) __builtin_amdgcn_mfma_f32_16x16x32_f16(A,B,C,0,0,0)

#define QS   40            // row stride in halfs (80 B: 16B-aligned rows)
#define HSZ  (32*QS)       // one 32-row head region
#define OFFK (6*HSZ)
#define OFFV (12*HSZ)
#define AOS  200           // sAO row stride in halfs (400 B)

// f16 weight cache offsets (in halfs) inside d_ws
#define W_QKV   0
#define W_QKVC  110592
#define W_PROJ  221184
#define W_PROJC 258048
#define W_TOTAL 294912

__global__ void cvt_weights(const float* __restrict__ a, const float* __restrict__ b,
                            const float* __restrict__ c, const float* __restrict__ d,
                            f16* __restrict__ ws)
{
    int i = blockIdx.x * 256 + threadIdx.x;
    if (i < 110592) {
        ws[W_QKV  + i] = (f16)a[i];
        ws[W_QKVC + i] = (f16)b[i];
    } else {
        int j = i - 110592;
        if (j < 36864) {
            ws[W_PROJ  + j] = (f16)c[j];
            ws[W_PROJC + j] = (f16)d[j];
        }
    }
}

template<bool W16>
__device__ __forceinline__ f16x8 ldw8(const void* base, int idx)
{
    if constexpr (W16) {
        return *(const f16x8*)((const f16*)base + idx);
    } else {
        const float* p = (const float*)base + idx;
        float4 u = *(const float4*)p;
        float4 v = *(const float4*)(p + 4);
        f16x8 r;
        r[0]=(f16)u.x; r[1]=(f16)u.y; r[2]=(f16)u.z; r[3]=(f16)u.w;
        r[4]=(f16)v.x; r[5]=(f16)v.y; r[6]=(f16)v.z; r[7]=(f16)v.w;
        return r;
    }
}

__device__ __forceinline__ f16x8 ldx8(const float* p)
{
    float4 u = *(const float4*)p;
    float4 v = *(const float4*)(p + 4);
    f16x8 r;
    r[0]=(f16)u.x; r[1]=(f16)u.y; r[2]=(f16)u.z; r[3]=(f16)u.w;
    r[4]=(f16)v.x; r[5]=(f16)v.y; r[6]=(f16)v.z; r[7]=(f16)v.w;
    return r;
}

template<bool W16>
__global__ __launch_bounds__(256, 2)
void vsa_kernel(const float* __restrict__ x,
                const float* __restrict__ qkv_w, const float* __restrict__ qkv_b,
                const float* __restrict__ proj_w, const float* __restrict__ proj_b,
                const float* __restrict__ rpb_table, const float* __restrict__ temperature,
                const float* __restrict__ qkvC_w, const float* __restrict__ dw_w,
                const float* __restrict__ projC_w, const float* __restrict__ projC_b,
                const float* __restrict__ gs_w1, const float* __restrict__ gs_b1,
                const float* __restrict__ bn_g, const float* __restrict__ bn_b,
                const float* __restrict__ bn_m, const float* __restrict__ bn_v,
                const float* __restrict__ gs_w2, const float* __restrict__ gs_b2,
                const f16* __restrict__ ws, float* __restrict__ out)
{
    // LDS: 46080 (pool) + 12800 (sAO) + 128 = 59008 B -> 2 blocks/CU (8 waves)
    __shared__ __align__(16) unsigned char pool[18*HSZ*2];   // sQKV | sOut(fp32) alias
    __shared__ __align__(16) f16 sAO[32*AOS];
    __shared__ float aspl[32];

    f16* sQKV = (f16*)pool;

    const int t    = threadIdx.x;
    const int w    = t >> 6;         // wave 0..3
    const int lane = t & 63;
    const int l15  = lane & 15;
    const int g    = lane >> 4;      // 0..3

    const float* xb = x + (size_t)blockIdx.x * 6144;
    const f32x4 z4 = {0.f, 0.f, 0.f, 0.f};

    // ---- spatial gate (wave 0): pooled == 1/32 exactly (softmax rows sum to 1) ----
    if (t < 32) {
        float y1 = gs_b1[t];
        #pragma unroll
        for (int hh = 0; hh < 6; ++hh) y1 += gs_w1[t*54 + hh*9 + 4] * (1.0f/32.0f);
        y1 = (y1 - bn_m[t]) * rsqrtf(bn_v[t] + 1e-5f) * bn_g[t] + bn_b[t];
        float y2 = gs_b2[t];
        #pragma unroll
        for (int c = 0; c < 32; ++c)
            y2 += gs_w2[t*288 + c*9 + 4] * __shfl(y1, c);
        aspl[t] = 1.0f + y2;
    }

    // ---- X as MFMA B-fragments in registers (reused by GEMM1 and GEMM1C) ----
    f16x8 xf[6][2];
    #pragma unroll
    for (int kt = 0; kt < 6; ++kt)
        #pragma unroll
        for (int nt = 0; nt < 2; ++nt)
            xf[kt][nt] = ldx8(xb + (nt*16 + l15)*192 + kt*32 + g*8);

    // ========== GEMM1: qkv^T = qkv_w @ x^T  (kt-outer, 9 loads in flight) ==========
    {
        const void* wb = W16 ? (const void*)ws : (const void*)qkv_w;
        f32x4 acc[9][2];
        #pragma unroll
        for (int mt = 0; mt < 9; ++mt) { acc[mt][0] = z4; acc[mt][1] = z4; }
        #pragma unroll
        for (int kt = 0; kt < 6; ++kt) {
            f16x8 af[9];
            #pragma unroll
            for (int mt = 0; mt < 9; ++mt)
                af[mt] = ldw8<W16>(wb, (144*w + 16*mt + l15)*192 + kt*32 + g*8);
            #pragma unroll
            for (int mt = 0; mt < 9; ++mt) {
                acc[mt][0] = MFMA16(af[mt], xf[kt][0], acc[mt][0]);
                acc[mt][1] = MFMA16(af[mt], xf[kt][1], acc[mt][1]);
            }
        }
        const float scale = 0.17677669529663687f;  // 32^-0.5
        #pragma unroll
        for (int mt = 0; mt < 9; ++mt) {
            int chb   = 144*w + 16*mt;
            int which = chb / 192;              // 0=q 1=k 2=v (wave-uniform)
            int hh    = (chb % 192) >> 5;
            int db    = (chb & 31) + 4*g;
            float4 bi = *(const float4*)(qkv_b + chb + 4*g);
            #pragma unroll
            for (int nt = 0; nt < 2; ++nt) {
                int token = 16*nt + l15;
                f32x4 a = acc[mt][nt];
                if (which == 0) {
                    f16x4 o;
                    o[0]=(f16)((a[0]+bi.x)*scale); o[1]=(f16)((a[1]+bi.y)*scale);
                    o[2]=(f16)((a[2]+bi.z)*scale); o[3]=(f16)((a[3]+bi.w)*scale);
                    *(f16x4*)(sQKV + hh*HSZ + token*QS + db) = o;
                } else if (which == 1) {
                    f16x4 o;
                    o[0]=(f16)(a[0]+bi.x); o[1]=(f16)(a[1]+bi.y);
                    o[2]=(f16)(a[2]+bi.z); o[3]=(f16)(a[3]+bi.w);
                    *(f16x4*)(sQKV + OFFK + hh*HSZ + token*QS + db) = o;
                } else {   // V stored transposed: [d][token] for branch-1 PV
                    f16* sV = sQKV + OFFV + hh*HSZ;
                    sV[(db+0)*QS + token] = (f16)(a[0]+bi.x);
                    sV[(db+1)*QS + token] = (f16)(a[1]+bi.y);
                    sV[(db+2)*QS + token] = (f16)(a[2]+bi.z);
                    sV[(db+3)*QS + token] = (f16)(a[3]+bi.w);
                }
            }
        }
    }
    __syncthreads();   // b1: Q/K/V ready

    // ========== branch-1 attention: head-tasks 0-3 on waves, 4-5 on waves 0,1 =======
    #pragma unroll 1
    for (int hi = 0; hi < 2; ++hi) {
        int h = w + 4*hi;
        if (h < 6) {
            f16* sQh = sQKV + h*HSZ;
            f16* sKh = sQKV + OFFK + h*HSZ;
            f16* sVh = sQKV + OFFV + h*HSZ;
            f16x8 qa[2], kb[2];
            #pragma unroll
            for (int mt = 0; mt < 2; ++mt)
                qa[mt] = *(const f16x8*)(sQh + (16*mt + l15)*QS + 8*g);
            #pragma unroll
            for (int nt = 0; nt < 2; ++nt)
                kb[nt] = *(const f16x8*)(sKh + (16*nt + l15)*QS + 8*g);
            f32x4 s[2][2];
            #pragma unroll
            for (int mt = 0; mt < 2; ++mt)
                #pragma unroll
                for (int nt = 0; nt < 2; ++nt)
                    s[mt][nt] = MFMA16(qa[mt], kb[nt], z4);

            float pr[2][2][4];
            #pragma unroll
            for (int mt = 0; mt < 2; ++mt)
                #pragma unroll
                for (int nt = 0; nt < 2; ++nt)
                    #pragma unroll
                    for (int r = 0; r < 4; ++r) {
                        int m = 16*mt + 4*g + r, n = 16*nt + l15;
                        int dh = (m>>3) - (n>>3) + 3;
                        int dwd = (m&7) - (n&7) + 7;
                        pr[mt][nt][r] = s[mt][nt][r] + rpb_table[(dh*15+dwd)*6 + h];
                    }
            #pragma unroll
            for (int mt = 0; mt < 2; ++mt)
                #pragma unroll
                for (int r = 0; r < 4; ++r) {
                    float mx = fmaxf(pr[mt][0][r], pr[mt][1][r]);
                    mx = fmaxf(mx, __shfl_xor(mx, 1));
                    mx = fmaxf(mx, __shfl_xor(mx, 2));
                    mx = fmaxf(mx, __shfl_xor(mx, 4));
                    mx = fmaxf(mx, __shfl_xor(mx, 8));
                    float e0 = __expf(pr[mt][0][r] - mx);
                    float e1 = __expf(pr[mt][1][r] - mx);
                    float sm = e0 + e1;
                    sm += __shfl_xor(sm, 1);
                    sm += __shfl_xor(sm, 2);
                    sm += __shfl_xor(sm, 4);
                    sm += __shfl_xor(sm, 8);
                    float inv = 1.0f / sm;
                    pr[mt][0][r] = e0*inv;
                    pr[mt][1][r] = e1*inv;
                }
            // P overwrites Q region (only this wave touches head h's Q)
            #pragma unroll
            for (int mt = 0; mt < 2; ++mt)
                #pragma unroll
                for (int nt = 0; nt < 2; ++nt)
                    #pragma unroll
                    for (int r = 0; r < 4; ++r)
                        sQh[(16*mt + 4*g + r)*QS + 16*nt + l15] = (f16)pr[mt][nt][r];

            // O^T = V^T @ P^T
            f16x8 va[2], pb[2];
            #pragma unroll
            for (int mt = 0; mt < 2; ++mt)
                va[mt] = *(const f16x8*)(sVh + (16*mt + l15)*QS + 8*g);
            #pragma unroll
            for (int nt = 0; nt < 2; ++nt)
                pb[nt] = *(const f16x8*)(sQh + (16*nt + l15)*QS + 8*g);
            #pragma unroll
            for (int mt = 0; mt < 2; ++mt)
                #pragma unroll
                for (int nt = 0; nt < 2; ++nt) {
                    f32x4 o = MFMA16(va[mt], pb[nt], z4);
                    int token = 16*nt + l15;
                    int dbv = 16*mt + 4*g;
                    f16x4 ov;
                    ov[0]=(f16)o[0]; ov[1]=(f16)o[1]; ov[2]=(f16)o[2]; ov[3]=(f16)o[3];
                    *(f16x4*)(sAO + token*AOS + h*32 + dbv) = ov;
                }
        }
    }
    __syncthreads();   // b2: sAO (branch1) ready

    // ========== proj GEMM (wave w -> cols 48w..48w+47), acc in regs ==========
    f32x4 acc1[2][3];
    {
        const void* wb = W16 ? (const void*)(ws + W_PROJ) : (const void*)proj_w;
        #pragma unroll
        for (int ct = 0; ct < 3; ++ct) {
            float bi = proj_b[48*w + 16*ct + l15];
            f32x4 b4 = {bi, bi, bi, bi};
            acc1[0][ct] = b4; acc1[1][ct] = b4;
        }
        #pragma unroll
        for (int kt = 0; kt < 6; ++kt) {
            f16x8 aa[2], bb[3];
            #pragma unroll
            for (int mt = 0; mt < 2; ++mt)
                aa[mt] = *(const f16x8*)(sAO + (16*mt + l15)*AOS + kt*32 + 8*g);
            #pragma unroll
            for (int ct = 0; ct < 3; ++ct)
                bb[ct] = ldw8<W16>(wb, (48*w + 16*ct + l15)*192 + kt*32 + 8*g);
            #pragma unroll
            for (int mt = 0; mt < 2; ++mt)
                #pragma unroll
                for (int ct = 0; ct < 3; ++ct)
                    acc1[mt][ct] = MFMA16(aa[mt], bb[ct], acc1[mt][ct]);
        }
    }

    // ========== GEMM1C: Y = qkvC_w @ x^T (kt-outer); q/k ch-major, v token-major ====
    {
        const void* wb = W16 ? (const void*)(ws + W_QKVC) : (const void*)qkvC_w;
        f32x4 acc[9][2];
        #pragma unroll
        for (int mt = 0; mt < 9; ++mt) { acc[mt][0] = z4; acc[mt][1] = z4; }
        #pragma unroll
        for (int kt = 0; kt < 6; ++kt) {
            f16x8 af[9];
            #pragma unroll
            for (int mt = 0; mt < 9; ++mt)
                af[mt] = ldw8<W16>(wb, (144*w + 16*mt + l15)*192 + kt*32 + g*8);
            #pragma unroll
            for (int mt = 0; mt < 9; ++mt) {
                acc[mt][0] = MFMA16(af[mt], xf[kt][0], acc[mt][0]);
                acc[mt][1] = MFMA16(af[mt], xf[kt][1], acc[mt][1]);
            }
        }
        #pragma unroll
        for (int mt = 0; mt < 9; ++mt) {
            int chb   = 144*w + 16*mt;
            int which = chb / 192;
            int hh    = (chb % 192) >> 5;
            int db    = (chb & 31) + 4*g;
            f16* region = sQKV + which*(6*HSZ) + hh*HSZ;
            #pragma unroll
            for (int nt = 0; nt < 2; ++nt) {
                int token = 16*nt + l15;
                f32x4 a = acc[mt][nt];
                if (which == 2) {       // Yv token-major [n][dv] for vectorized conv
                    f16x4 o;
                    o[0]=(f16)a[0]; o[1]=(f16)a[1]; o[2]=(f16)a[2]; o[3]=(f16)a[3];
                    *(f16x4*)(region + token*QS + db) = o;
                } else {                // Yq/Yk channel-major [d][n]
                    region[(db+0)*QS + token] = (f16)a[0];
                    region[(db+1)*QS + token] = (f16)a[1];
                    region[(db+2)*QS + token] = (f16)a[2];
                    region[(db+3)*QS + token] = (f16)a[3];
                }
            }
        }
    }
    __syncthreads();   // b3: Y ready (proj's sAO reads also all done)

    // ========== branch-2 (MDTA): head-tasks 0-3 / 4-5, vectorized depthwise =========
    #pragma unroll 1
    for (int hi = 0; hi < 2; ++hi) {
        int h = w + 4*hi;
        if (h < 6) {
            f16* sQh = sQKV + h*HSZ;
            f16* sKh = sQKV + OFFK + h*HSZ;
            f16* sVh = sQKV + OFFV + h*HSZ;
            f16x8 qa[2], kb[2], vb[2];
            // q/k: depthwise 3x3 (3 vector row reads) + l2norm
            #pragma unroll
            for (int mt = 0; mt < 2; ++mt) {
                int d = 16*mt + l15;
                #pragma unroll
                for (int qk = 0; qk < 2; ++qk) {
                    int ch = qk*192 + h*32 + d;
                    const float* wp = dw_w + ch*9;
                    float wr[9];
                    #pragma unroll
                    for (int i2 = 0; i2 < 9; ++i2) wr[i2] = wp[i2];
                    const f16* yr = (qk ? sKh : sQh) + d*QS;
                    f16x8 row8[3];
                    #pragma unroll
                    for (int dh2 = 0; dh2 < 3; ++dh2) {
                        int h2 = g + dh2 - 1;
                        f16x8 rv;
                        if (h2 >= 0 && h2 < 4) rv = *(const f16x8*)(yr + 8*h2);
                        else { rv[0]=0;rv[1]=0;rv[2]=0;rv[3]=0;rv[4]=0;rv[5]=0;rv[6]=0;rv[7]=0; }
                        row8[dh2] = rv;
                    }
                    float z[8], ss = 0.f;
                    #pragma unroll
                    for (int b2 = 0; b2 < 8; ++b2) {
                        float s2 = 0.f;
                        #pragma unroll
                        for (int dh2 = 0; dh2 < 3; ++dh2)
                            #pragma unroll
                            for (int dw2 = 0; dw2 < 3; ++dw2) {
                                int w2 = b2 + dw2 - 1;
                                if (w2 >= 0 && w2 < 8)
                                    s2 += wr[dh2*3+dw2] * (float)row8[dh2][w2];
                            }
                        z[b2] = s2; ss += s2*s2;
                    }
                    ss += __shfl_xor(ss, 16);
                    ss += __shfl_xor(ss, 32);
                    float inv = 1.0f / fmaxf(sqrtf(ss), 1e-12f);
                    if (qk == 0) {
                        #pragma unroll
                        for (int b2 = 0; b2 < 8; ++b2) qa[mt][b2] = (f16)(z[b2]*inv);
                    } else {
                        #pragma unroll
                        for (int b2 = 0; b2 < 8; ++b2) kb[mt][b2] = (f16)(z[b2]*inv);
                    }
                }
            }
            // vc: depthwise on token-major Yv; per-lane channels 8g..8g+7
            float4 wv4[18];
            {
                const float* wpv = dw_w + (size_t)(384 + h*32 + 8*g)*9;
                #pragma unroll
                for (int i2 = 0; i2 < 18; ++i2)
                    wv4[i2] = *(const float4*)(wpv + 4*i2);
            }
            #pragma unroll
            for (int nt = 0; nt < 2; ++nt) {
                int n = 16*nt + l15;
                int nh = n >> 3, nw = n & 7;
                float a8[8];
                #pragma unroll
                for (int b2 = 0; b2 < 8; ++b2) a8[b2] = 0.f;
                #pragma unroll
                for (int dh2 = 0; dh2 < 3; ++dh2) {
                    int h2 = nh + dh2 - 1;
                    #pragma unroll
                    for (int dw2 = 0; dw2 < 3; ++dw2) {
                        int w2 = nw + dw2 - 1;
                        if (h2 >= 0 && h2 < 4 && w2 >= 0 && w2 < 8) {
                            f16x8 v8 = *(const f16x8*)(sVh + (h2*8+w2)*QS + 8*g);
                            int tap = dh2*3 + dw2;
                            #pragma unroll
                            for (int b2 = 0; b2 < 8; ++b2) {
                                int wi = b2*9 + tap;
                                float wt = (&wv4[wi>>2].x)[wi&3];
                                a8[b2] += wt * (float)v8[b2];
                            }
                        }
                    }
                }
                #pragma unroll
                for (int b2 = 0; b2 < 8; ++b2) vb[nt][b2] = (f16)a8[b2];
            }
            // S_c = qc kc^T * temp + |d-d'|*dlog ; softmax over d'
            float temph = temperature[h];
            float dlog  = logf(1.0f - exp2f(-2.0f - (2.0f*(float)h)/3.0f));
            f32x4 s[2][2];
            #pragma unroll
            for (int mt = 0; mt < 2; ++mt)
                #pragma unroll
                for (int nt = 0; nt < 2; ++nt)
                    s[mt][nt] = MFMA16(qa[mt], kb[nt], z4);
            float pr[2][2][4];
            #pragma unroll
            for (int mt = 0; mt < 2; ++mt)
                #pragma unroll
                for (int nt = 0; nt < 2; ++nt)
                    #pragma unroll
                    for (int r = 0; r < 4; ++r) {
                        int di = 16*mt + 4*g + r, dj = 16*nt + l15;
                        pr[mt][nt][r] = s[mt][nt][r]*temph + fabsf((float)(di - dj))*dlog;
                    }
            #pragma unroll
            for (int mt = 0; mt < 2; ++mt)
                #pragma unroll
                for (int r = 0; r < 4; ++r) {
                    float mx = fmaxf(pr[mt][0][r], pr[mt][1][r]);
                    mx = fmaxf(mx, __shfl_xor(mx, 1));
                    mx = fmaxf(mx, __shfl_xor(mx, 2));
                    mx = fmaxf(mx, __shfl_xor(mx, 4));
                    mx = fmaxf(mx, __shfl_xor(mx, 8));
                    float e0 = __expf(pr[mt][0][r] - mx);
                    float e1 = __expf(pr[mt][1][r] - mx);
                    float sm = e0 + e1;
                    sm += __shfl_xor(sm, 1);
                    sm += __shfl_xor(sm, 2);
                    sm += __shfl_xor(sm, 4);
                    sm += __shfl_xor(sm, 8);
                    float inv = 1.0f / sm;
                    pr[mt][0][r] = e0*inv;
                    pr[mt][1][r] = e1*inv;
                }
            // P_c overwrites Yq region (consumed into qa; only this wave uses head h)
            #pragma unroll
            for (int mt = 0; mt < 2; ++mt)
                #pragma unroll
                for (int nt = 0; nt < 2; ++nt)
                    #pragma unroll
                    for (int r = 0; r < 4; ++r)
                        sQh[(16*mt + 4*g + r)*QS + 16*nt + l15] = (f16)pr[mt][nt][r];
            // x2pre[d][n] = P_c @ vc -> sAO (branch-1 data in sAO dead after b3)
            f16x8 pa[2];
            #pragma unroll
            for (int mt = 0; mt < 2; ++mt)
                pa[mt] = *(const f16x8*)(sQh + (16*mt + l15)*QS + 8*g);
            #pragma unroll
            for (int mt = 0; mt < 2; ++mt)
                #pragma unroll
                for (int nt = 0; nt < 2; ++nt) {
                    f32x4 o = MFMA16(pa[mt], vb[nt], z4);
                    int token = 16*nt + l15;
                    int dbv = 16*mt + 4*g;
                    f16x4 ov;
                    ov[0]=(f16)o[0]; ov[1]=(f16)o[1]; ov[2]=(f16)o[2]; ov[3]=(f16)o[3];
                    *(f16x4*)(sAO + token*AOS + h*32 + dbv) = ov;
                }
        }
    }
    __syncthreads();   // b4: sAO (branch2) ready

    // ========== projC GEMM ==========
    f32x4 acc2[2][3];
    {
        const void* wb = W16 ? (const void*)(ws + W_PROJC) : (const void*)projC_w;
        #pragma unroll
        for (int ct = 0; ct < 3; ++ct) {
            float bi = projC_b[48*w + 16*ct + l15];
            f32x4 b4 = {bi, bi, bi, bi};
            acc2[0][ct] = b4; acc2[1][ct] = b4;
        }
        #pragma unroll
        for (int kt = 0; kt < 6; ++kt) {
            f16x8 aa[2], bb[3];
            #pragma unroll
            for (int mt = 0; mt < 2; ++mt)
                aa[mt] = *(const f16x8*)(sAO + (16*mt + l15)*AOS + kt*32 + 8*g);
            #pragma unroll
            for (int ct = 0; ct < 3; ++ct)
                bb[ct] = ldw8<W16>(wb, (48*w + 16*ct + l15)*192 + kt*32 + 8*g);
            #pragma unroll
            for (int mt = 0; mt < 2; ++mt)
                #pragma unroll
                for (int ct = 0; ct < 3; ++ct)
                    acc2[mt][ct] = MFMA16(aa[mt], bb[ct], acc2[mt][ct]);
        }
    }

    // ========== epilogue: stage fp32 result in LDS, coalesced float4 store =========
    float* sOut = (float*)pool;   // sQKV fully dead after b4
    #pragma unroll
    for (int mt = 0; mt < 2; ++mt)
        #pragma unroll
        for (int r = 0; r < 4; ++r) {
            int m = 16*mt + 4*g + r;
            float asp = aspl[m];
            #pragma unroll
            for (int ct = 0; ct < 3; ++ct) {
                int c = 48*w + 16*ct + l15;
                sOut[m*192 + c] = acc1[mt][ct][r] + acc2[mt][ct][r]*asp;
            }
        }
    __syncthreads();   // b5
    {
        const float4* sOv = (const float4*)sOut;
        float4* ob4 = (float4*)(out + (size_t)blockIdx.x * 6144);
        #pragma unroll
        for (int it = 0; it < 6; ++it)
            ob4[t + 256*it] = sOv[t + 256*it];
    }
}

extern "C" void kernel_launch(void* const* d_in, const int* in_sizes, int n_in,
                              void* d_out, int out_size, void* d_ws, size_t ws_size,
                              hipStream_t stream) {
    (void)n_in; (void)out_size;
    const float* x         = (const float*)d_in[0];
    const float* qkv_w     = (const float*)d_in[1];
    const float* qkv_b     = (const float*)d_in[2];
    const float* proj_w    = (const float*)d_in[3];
    const float* proj_b    = (const float*)d_in[4];
    const float* rpb_table = (const float*)d_in[5];
    const float* temp      = (const float*)d_in[6];
    const float* qkvC_w    = (const float*)d_in[7];
    const float* dw_w      = (const float*)d_in[8];
    const float* projC_w   = (const float*)d_in[9];
    const float* projC_b   = (const float*)d_in[10];
    const float* gs_w1     = (const float*)d_in[11];
    const float* gs_b1     = (const float*)d_in[12];
    const float* bn_g      = (const float*)d_in[13];
    const float* bn_b      = (const float*)d_in[14];
    const float* bn_m      = (const float*)d_in[15];
    const float* bn_v      = (const float*)d_in[16];
    const float* gs_w2     = (const float*)d_in[17];
    const float* gs_b2     = (const float*)d_in[18];
    float* out = (float*)d_out;

    int B = in_sizes[0] / (32 * 192);   // 4096
    bool use_ws = (d_ws != nullptr) && (ws_size >= (size_t)W_TOTAL * sizeof(f16));
    if (use_ws) {
        cvt_weights<<<576, 256, 0, stream>>>(qkv_w, qkvC_w, proj_w, projC_w, (f16*)d_ws);
        vsa_kernel<true><<<B, 256, 0, stream>>>(x, qkv_w, qkv_b, proj_w, proj_b,
                                                rpb_table, temp, qkvC_w, dw_w,
                                                projC_w, projC_b, gs_w1, gs_b1,
                                                bn_g, bn_b, bn_m, bn_v, gs_w2, gs_b2,
                                                (const f16*)d_ws, out);
    } else {
        vsa_kernel<false><<<B, 256, 0, stream>>>(x, qkv_w, qkv_b, proj_w, proj_b,
                                                 rpb_table, temp, qkvC_w, dw_w,
                                                 projC_w, projC_b, gs_w1, gs_b1,
                                                 bn_g, bn_b, bn_m, bn_v, gs_w2, gs_b2,
                                                 nullptr, out);
    }
}